// Round 6
// baseline (117.175 us; speedup 1.0000x reference)
//
#include <hip/hip_runtime.h>
#include <math.h>

#define NB 8
#define NQ 256
#define NK 256
#define DIN 10
#define FDIM 64
#define HIDDEN 256
#define NH 8
#define ROWS_PER_BLK 4

#define FSTRIDE 64    // shorts per feat row; XOR-swizzled 8-short col-blocks
#define HSTRIDE 264   // shorts per h row (256 + 8 pad) -> 528 B

typedef float f32x4 __attribute__((ext_vector_type(4)));
typedef float f32x2 __attribute__((ext_vector_type(2)));
typedef short bf16x8 __attribute__((ext_vector_type(8)));

__device__ __forceinline__ short f2bf(float f) {
    return (short)((__float_as_uint(f) + 0x8000u) >> 16);
}
// pack two floats -> two bf16 in ONE instr (RTNE). a -> low half, b -> high.
__device__ __forceinline__ unsigned cvtpk(float a, float b) {
    unsigned r;
    asm("v_cvt_pk_bf16_f32 %0, %1, %2" : "=v"(r) : "v"(a), "v"(b));
    return r;
}
__device__ __forceinline__ float rcpf(float x) { return __builtin_amdgcn_rcpf(x); }
__device__ __forceinline__ float ex2f(float x) { return __builtin_amdgcn_exp2f(x); }
__device__ __forceinline__ float sqtf(float x) { return __builtin_amdgcn_sqrtf(x); }

__device__ __forceinline__ void four4(float x, float* dst) {
    float s1 = __sinf(x), c1 = __cosf(x);
    float s2 = 2.f * s1 * c1, c2 = 1.f - 2.f * s1 * s1;
    float s4 = 2.f * s2 * c2, c4 = 1.f - 2.f * s2 * s2;
    float s8 = 2.f * s4 * c4, c8 = 1.f - 2.f * s4 * s4;
    dst[0] = s1; dst[1] = s2; dst[2] = s4; dst[3] = s8;
    dst[4] = c1; dst[5] = c2; dst[6] = c4; dst[7] = c8;
}
__device__ __forceinline__ void four2(float x, float* dst) {
    float s1 = __sinf(x), c1 = __cosf(x);
    dst[0] = s1; dst[1] = 2.f * s1 * c1;
    dst[2] = c1; dst[3] = 1.f - 2.f * s1 * s1;
}

// r6 = r5 + feature-phase overlap (one attributable change):
//   features(row+1) are computed by WAVES 4-7 (one thread per pair, full
//   64-feat row) inside the chunk-3 post-bar2 region, concurrent with
//   waves 0-3's GEMM2(c3). The dedicated serial per-row feature phase is
//   deleted (row 0 keeps a prologue). Hazards:
//     feat_s(row) last read: G1(c3), before bar1(c3)  -> writes after
//       bar2(c3) are 2 barriers later. WAR safe.
//     feat_s(row+1) reads: G1(row+1,c0), after the row-rollover barrier
//       which seals the waves-4-7 writes. RAW safe.
//   No register state crosses a barrier (r3/r4 spill lesson): feat locals
//   die at their ds_writes, before the rollover barrier.
// Everything else identical to r5 (proven 51.2us): bias as C-in, packed-f32
// silu, raw rcp/sqrt/exp2-tanh, W2 in regs, scale folds W1,b1 x -log2(e),
// W2 x -ln(2).
__global__ __launch_bounds__(512, 4) void relfeat_mfma_kernel(
    const float* __restrict__ q, const float* __restrict__ k,
    const float* __restrict__ W1, const float* __restrict__ b1,
    const float* __restrict__ W2, const float* __restrict__ b2,
    float* __restrict__ out)
{
    __shared__ __align__(16) short feat_s[NK * FSTRIDE];   // 32768 B
    __shared__ __align__(16) short h_s[64 * HSTRIDE];      // 33792 B

    const int t = threadIdx.x;          // 0..511
    const int wave = t >> 6;            // 0..7
    const int lane15 = t & 15;
    const int quad = (t >> 4) & 3;
    const int p = t & 255;              // pair id (features: waves 4-7)
    const int b = blockIdx.x >> 6;
    const int i0 = (blockIdx.x & 63) * ROWS_PER_BLK;

    // ---- k-row for pair j = p (used by feature threads; cheap, uniform) ----
    const float* kp = k + ((size_t)b * NK + p) * DIN;
    const float k0 = kp[0], k3 = kp[3], k4 = kp[4], k5 = kp[5], k6 = kp[6],
                k7 = kp[7], k8 = kp[8];
    const float k_speed = sqtf(k5 * k5 + k6 * k6);   // row-invariant

    // ---- W2 fragments in regs (GEMM2 B-operand), scaled by -ln2 ----
    bf16x8 w2f[8];
    if (wave < 4) {
#pragma unroll
        for (int ks = 0; ks < 8; ++ks) {
            const float* wp = W2 + (size_t)(ks * 32 + quad * 8) * NH + (lane15 & 7);
            bf16x8 v;
#pragma unroll
            for (int e = 0; e < 8; ++e)
                v[e] = f2bf(-0.69314718f * wp[(size_t)e * NH]);
            w2f[ks] = v;
        }
    }

    // ---- W1 fragments (A operand), scaled by -log2e ----
    const int n0 = wave * 32;
    bf16x8 w1f[2][2];
#pragma unroll
    for (int nt = 0; nt < 2; ++nt)
#pragma unroll
        for (int ks = 0; ks < 2; ++ks) {
            const float* wp = W1 + (size_t)(ks * 32 + quad * 8) * HIDDEN
                              + (n0 + nt * 16 + lane15);
            bf16x8 v;
#pragma unroll
            for (int e = 0; e < 8; ++e)
                v[e] = f2bf(-1.44269504f * wp[(size_t)e * HIDDEN]);
            w1f[nt][ks] = v;
        }
    // bias fragment (MFMA C-in at ks=0), scaled by -log2e
    f32x4 b1c[2];
#pragma unroll
    for (int nt = 0; nt < 2; ++nt) {
        float4 bb = *(const float4*)&b1[n0 + nt * 16 + quad * 4];
        b1c[nt] = (f32x4){-1.44269504f * bb.x, -1.44269504f * bb.y,
                          -1.44269504f * bb.z, -1.44269504f * bb.w};
    }
    const float b2v = (lane15 < NH) ? b2[lane15] : 0.f;
    // G2 output pointer base (valid only when lane15 < NH; never deref'd else)
    float* const outp = out + ((size_t)b * NH + (lane15 & 7)) * NQ * NK
                        + wave * 16 + quad * 4;

    const int sw = p & 7;        // feature-store swizzle
    const int swr = lane15 & 7;  // feat B-frag read swizzle
    const f32x2 one2 = {1.f, 1.f};

    // ---- full 64-feature row for pair p (one thread per pair) ----
    // All locals die at the ds_writes -> nothing live across barriers.
    auto feat_full = [&](int irow) {
        const float* qp = q + ((size_t)b * NQ + irow) * DIN;
        const float q0 = qp[0], q3 = qp[3], q4 = qp[4], q5 = qp[5],
                    q6 = qp[6], q7 = qp[7], q8 = qp[8];
        const float dpx = k3 - q3, dpy = k4 - q4;
        const float dvx = k5 - q5, dvy = k6 - q6;
        const float dist = sqtf(dpx * dpx + dpy * dpy + 1e-6f);
        const float inv_dist = rcpf(dist + 0.1f);
        const float inv_d2 = rcpf(dist + 1e-6f);
        const float bear_x = dpx * inv_d2, bear_y = dpy * inv_d2;
        const float ata = bear_x * q7 + bear_y * q8;
        const float aspect = bear_x * k7 + bear_y * k8;
        const float dot_dp_dv = dpx * dvx + dpy * dvy;
        const float speed_sq = dvx * dvx + dvy * dvy;
        // tanh(relu(z)) = 1 - 2/(1 + 2^(2*log2e*z)), z >= 0
        const float z = fmaxf(0.f, -dot_dp_dv * rcpf(speed_sq + 1e-6f));
        const float ttca = 1.f - 2.f * rcpf(1.f + ex2f(2.88539008f * z));
        const float q_speed = sqtf(q5 * q5 + q6 * q6);
        const float delta_speed = k_speed - q_speed;

        float feat[FDIM];
        four4(dist,     feat + 0);
        four4(inv_dist, feat + 8);
        four4(ata,      feat + 16);
        four4(aspect,   feat + 24);
        four2(dpx,      feat + 32);
        four2(dpy,      feat + 36);
        four2(dvx,      feat + 40);
        four2(dvy,      feat + 44);
        four2(ttca,     feat + 48);
        feat[52] = feat[0]; feat[53] = feat[1];   // four2(dist) reuse
        feat[54] = feat[4]; feat[55] = feat[5];
        const bool st = (q0 == k0);               // same_team constants
        feat[56] = st ? 0.84147098f : 0.f;        // sin(1)/sin(0)
        feat[57] = st ? 0.90929743f : 0.f;        // sin(2)/sin(0)
        feat[58] = st ? 0.54030231f : 1.f;        // cos(1)/cos(0)
        feat[59] = st ? -0.41614684f : 1.f;       // cos(2)/cos(0)
        four2(delta_speed, feat + 60);

#pragma unroll
        for (int c8 = 0; c8 < 8; ++c8) {
            uint4 v;
            v.x = cvtpk(feat[c8 * 8 + 0], feat[c8 * 8 + 1]);
            v.y = cvtpk(feat[c8 * 8 + 2], feat[c8 * 8 + 3]);
            v.z = cvtpk(feat[c8 * 8 + 4], feat[c8 * 8 + 5]);
            v.w = cvtpk(feat[c8 * 8 + 6], feat[c8 * 8 + 7]);
            *(uint4*)&feat_s[p * FSTRIDE + ((c8 ^ sw) * 8)] = v;
        }
    };

    // ---- prologue: features(row 0) by waves 4-7 ----
    if (wave >= 4)
        feat_full(i0);
    __syncthreads();   // feat_s(row 0) ready

    // ================= row loop: 4 query rows =================
#pragma unroll 1
    for (int row = 0; row < ROWS_PER_BLK; ++row) {
        const int i = i0 + row;

        // ---- 4 chunks of 64 pairs ----
#pragma unroll 1
        for (int c = 0; c < 4; ++c) {
            const int p0 = c * 64;

            // GEMM1': bias rides as C-in on the ks=0 MFMAs
            f32x4 acc[2][4];
#pragma unroll
            for (int mt = 0; mt < 4; ++mt) {
                const int r2 = p0 + mt * 16 + lane15;
                const bf16x8 fb = *(const bf16x8*)
                    &feat_s[r2 * FSTRIDE + ((quad ^ swr) * 8)];
                acc[0][mt] = __builtin_amdgcn_mfma_f32_16x16x32_bf16(
                    w1f[0][0], fb, b1c[0], 0, 0, 0);
                acc[1][mt] = __builtin_amdgcn_mfma_f32_16x16x32_bf16(
                    w1f[1][0], fb, b1c[1], 0, 0, 0);
            }
#pragma unroll
            for (int mt = 0; mt < 4; ++mt) {
                const int r2 = p0 + mt * 16 + lane15;
                const bf16x8 fb = *(const bf16x8*)
                    &feat_s[r2 * FSTRIDE + (((4 + quad) ^ swr) * 8)];
#pragma unroll
                for (int nt = 0; nt < 2; ++nt)
                    acc[nt][mt] = __builtin_amdgcn_mfma_f32_16x16x32_bf16(
                        w1f[nt][1], fb, acc[nt][mt], 0, 0, 0);
            }

            // silu-COMPUTE into regs (no LDS): packed-f32 add/mul
            uint2 pk[2][4];
#pragma unroll
            for (int nt = 0; nt < 2; ++nt)
#pragma unroll
                for (int mt = 0; mt < 4; ++mt) {
                    const f32x4 a = acc[nt][mt];     // = -log2e * preact
                    const f32x2 a01 = {a[0], a[1]}, a23 = {a[2], a[3]};
                    const f32x2 e01 = {ex2f(a[0]), ex2f(a[1])};
                    const f32x2 e23 = {ex2f(a[2]), ex2f(a[3])};
                    const f32x2 t01 = e01 + one2;    // v_pk_add_f32
                    const f32x2 t23 = e23 + one2;
                    const f32x2 r01 = {rcpf(t01[0]), rcpf(t01[1])};
                    const f32x2 r23 = {rcpf(t23[0]), rcpf(t23[1])};
                    const f32x2 s01 = a01 * r01;     // v_pk_mul_f32
                    const f32x2 s23 = a23 * r23;     // = -1.4427*silu
                    pk[nt][mt].x = cvtpk(s01[0], s01[1]);
                    pk[nt][mt].y = cvtpk(s23[0], s23[1]);
                }

            __syncthreads();  // barrier#1: h_s(prev) fully consumed

            // only the 8 ds_write_b64 live between the barriers
#pragma unroll
            for (int nt = 0; nt < 2; ++nt)
#pragma unroll
                for (int mt = 0; mt < 4; ++mt) {
                    const int pair = mt * 16 + lane15;
                    const int hbase = n0 + nt * 16 + quad * 4;
                    *(uint2*)&h_s[pair * HSTRIDE + hbase] = pk[nt][mt];
                }
            __syncthreads();  // barrier#2: h_s(c) ready

            // post-bar2 region: waves 0-3 -> GEMM2(c); waves 4-7 at c==3 ->
            // features(row+1), written over the now-dead feat_s(row).
            if (wave < 4) {
                const int pw = wave * 16;
                f32x4 acc2 = (f32x4){b2v, b2v, b2v, b2v};
#pragma unroll
                for (int ks = 0; ks < 8; ++ks) {
                    const bf16x8 ha = *(const bf16x8*)&h_s[(pw + lane15) * HSTRIDE
                                                            + ks * 32 + quad * 8];
                    acc2 = __builtin_amdgcn_mfma_f32_16x16x32_bf16(ha, w2f[ks], acc2, 0, 0, 0);
                }
                if (lane15 < NH) {
                    float* op = outp + (size_t)i * NK + p0;
                    *(float4*)op = make_float4(acc2[0], acc2[1], acc2[2], acc2[3]);
                }
            } else if (c == 3 && row + 1 < ROWS_PER_BLK) {
                feat_full(i + 1);
            }
            // no end barrier: next chunk's GEMM1' touches only feat_s(row)
        }

        // row rollover: seals feat_s(row+1) writes before G1(row+1, c0);
        // also orders G2(row,c3) h_s reads before next row's h writes.
        if (row + 1 < ROWS_PER_BLK)
            __syncthreads();
    }
}

extern "C" void kernel_launch(void* const* d_in, const int* in_sizes, int n_in,
                              void* d_out, int out_size, void* d_ws, size_t ws_size,
                              hipStream_t stream) {
    const float* q  = (const float*)d_in[0];
    const float* k  = (const float*)d_in[1];
    const float* W1 = (const float*)d_in[2];
    const float* b1 = (const float*)d_in[3];
    const float* W2 = (const float*)d_in[4];
    const float* b2 = (const float*)d_in[5];
    float* out = (float*)d_out;

    dim3 grid(NB * NQ / ROWS_PER_BLK);  // 512 blocks = 2/CU, one dispatch round
    dim3 block(512);                    // 8 waves: 16 waves/CU resident
    relfeat_mfma_kernel<<<grid, block, 0, stream>>>(q, k, W1, b1, W2, b2, out);
}

// Round 7
// 108.236 us; speedup vs baseline: 1.0826x; 1.0826x over previous
//
#include <hip/hip_runtime.h>
#include <math.h>

#define NB 8
#define NQ 256
#define NK 256
#define DIN 10
#define FDIM 64
#define HIDDEN 256
#define NH 8
#define ROWS_PER_BLK 4

#define FSTRIDE 64    // shorts per feat row; XOR-swizzled 8-short col-blocks
#define HSTRIDE 264   // shorts per h row (256 + 8 pad) -> 528 B

typedef float f32x4 __attribute__((ext_vector_type(4)));
typedef float f32x2 __attribute__((ext_vector_type(2)));
typedef short bf16x8 __attribute__((ext_vector_type(8)));

__device__ __forceinline__ short f2bf(float f) {
    return (short)((__float_as_uint(f) + 0x8000u) >> 16);
}
// pack two floats -> two bf16 in ONE instr (RTNE). a -> low half, b -> high.
__device__ __forceinline__ unsigned cvtpk(float a, float b) {
    unsigned r;
    asm("v_cvt_pk_bf16_f32 %0, %1, %2" : "=v"(r) : "v"(a), "v"(b));
    return r;
}
__device__ __forceinline__ float rcpf(float x) { return __builtin_amdgcn_rcpf(x); }
__device__ __forceinline__ float ex2f(float x) { return __builtin_amdgcn_exp2f(x); }
__device__ __forceinline__ float sqtf(float x) { return __builtin_amdgcn_sqrtf(x); }

__device__ __forceinline__ void four4(float x, float* dst) {
    float s1 = __sinf(x), c1 = __cosf(x);
    float s2 = 2.f * s1 * c1, c2 = 1.f - 2.f * s1 * s1;
    float s4 = 2.f * s2 * c2, c4 = 1.f - 2.f * s2 * s2;
    float s8 = 2.f * s4 * c4, c8 = 1.f - 2.f * s4 * s4;
    dst[0] = s1; dst[1] = s2; dst[2] = s4; dst[3] = s8;
    dst[4] = c1; dst[5] = c2; dst[6] = c4; dst[7] = c8;
}
__device__ __forceinline__ void four2(float x, float* dst) {
    float s1 = __sinf(x), c1 = __cosf(x);
    dst[0] = s1; dst[1] = 2.f * s1 * c1;
    dst[2] = c1; dst[3] = 1.f - 2.f * s1 * s1;
}

// r7 = r6's feature-overlap structure with the SPILL MECHANISM fixed:
//   r3/r4/r6 all spilled because the backend targets the 8-waves/EU tier
//   (VGPR<=64; launch_bounds' 2nd arg is only a MIN) and spills cold code
//   rather than dropping to the 128-VGPR tier.
//   Fix 1: amdgpu_waves_per_eu(4,4) pins the tier -> 128 VGPR authorized,
//          and min=4 keeps 2 blocks/CU (16 waves) exactly as now.
//   Fix 2: feature row STREAMED 8-at-a-time (compute->cvtpk->ds_write per
//          c8 group; only dist's 4 trig values persist) -> peak transient
//          ~12 floats instead of a 64-float array.
// Overlap (validated correct in r6): features(row+1) on waves 4-7 inside
// the chunk-3 post-bar2 region, concurrent with waves 0-3's GEMM2(c3);
// serial per-row feature phase deleted; row-rollover barrier seals
// feat_s(row+1) before G1(row+1,c0).
// Body otherwise identical to r5 (51.2us proven): bias as C-in, packed-f32
// silu, raw rcp/sqrt/exp2-tanh, W2 in regs; W1,b1 x -log2(e), W2 x -ln(2).
__global__ __attribute__((amdgpu_flat_work_group_size(512, 512),
                          amdgpu_waves_per_eu(4, 4)))
void relfeat_mfma_kernel(
    const float* __restrict__ q, const float* __restrict__ k,
    const float* __restrict__ W1, const float* __restrict__ b1,
    const float* __restrict__ W2, const float* __restrict__ b2,
    float* __restrict__ out)
{
    __shared__ __align__(16) short feat_s[NK * FSTRIDE];   // 32768 B
    __shared__ __align__(16) short h_s[64 * HSTRIDE];      // 33792 B

    const int t = threadIdx.x;          // 0..511
    const int wave = t >> 6;            // 0..7
    const int lane15 = t & 15;
    const int quad = (t >> 4) & 3;
    const int p = t & 255;              // pair id (features: waves 4-7)
    const int b = blockIdx.x >> 6;
    const int i0 = (blockIdx.x & 63) * ROWS_PER_BLK;

    // ---- k-row for pair j = p: block-invariant, cache in regs ----
    const float* kp = k + ((size_t)b * NK + p) * DIN;
    const float k0 = kp[0], k3 = kp[3], k4 = kp[4], k5 = kp[5], k6 = kp[6],
                k7 = kp[7], k8 = kp[8];
    const float k_speed = sqtf(k5 * k5 + k6 * k6);   // row-invariant

    // ---- W2 fragments in regs (GEMM2 B-operand), scaled by -ln2 ----
    bf16x8 w2f[8];
    if (wave < 4) {
#pragma unroll
        for (int ks = 0; ks < 8; ++ks) {
            const float* wp = W2 + (size_t)(ks * 32 + quad * 8) * NH + (lane15 & 7);
            bf16x8 v;
#pragma unroll
            for (int e = 0; e < 8; ++e)
                v[e] = f2bf(-0.69314718f * wp[(size_t)e * NH]);
            w2f[ks] = v;
        }
    }

    // ---- W1 fragments (A operand), scaled by -log2e ----
    const int n0 = wave * 32;
    bf16x8 w1f[2][2];
#pragma unroll
    for (int nt = 0; nt < 2; ++nt)
#pragma unroll
        for (int ks = 0; ks < 2; ++ks) {
            const float* wp = W1 + (size_t)(ks * 32 + quad * 8) * HIDDEN
                              + (n0 + nt * 16 + lane15);
            bf16x8 v;
#pragma unroll
            for (int e = 0; e < 8; ++e)
                v[e] = f2bf(-1.44269504f * wp[(size_t)e * HIDDEN]);
            w1f[nt][ks] = v;
        }
    // bias fragment (MFMA C-in at ks=0), scaled by -log2e
    f32x4 b1c[2];
#pragma unroll
    for (int nt = 0; nt < 2; ++nt) {
        float4 bb = *(const float4*)&b1[n0 + nt * 16 + quad * 4];
        b1c[nt] = (f32x4){-1.44269504f * bb.x, -1.44269504f * bb.y,
                          -1.44269504f * bb.z, -1.44269504f * bb.w};
    }
    const float b2v = (lane15 < NH) ? b2[lane15] : 0.f;
    // G2 output pointer base (valid only when lane15 < NH; never deref'd else)
    float* const outp = out + ((size_t)b * NH + (lane15 & 7)) * NQ * NK
                        + wave * 16 + quad * 4;

    const int sw = p & 7;        // feature-store swizzle
    const int swr = lane15 & 7;  // feat B-frag read swizzle
    const f32x2 one2 = {1.f, 1.f};

    // pack 8 floats -> one uint4 -> one ds_write_b128 (c8 compile-time)
    auto fstore = [&](int c8, const float* f8) {
        uint4 v;
        v.x = cvtpk(f8[0], f8[1]);
        v.y = cvtpk(f8[2], f8[3]);
        v.z = cvtpk(f8[4], f8[5]);
        v.w = cvtpk(f8[6], f8[7]);
        *(uint4*)&feat_s[p * FSTRIDE + ((c8 ^ sw) * 8)] = v;
    };
    // ---- full 64-feature row, STREAMED 8-at-a-time (low reg pressure) ----
    auto feat_full = [&](int irow) {
        const float* qp = q + ((size_t)b * NQ + irow) * DIN;
        const float q0 = qp[0], q3 = qp[3], q4 = qp[4], q5 = qp[5],
                    q6 = qp[6], q7 = qp[7], q8 = qp[8];
        const float dpx = k3 - q3, dpy = k4 - q4;
        const float dvx = k5 - q5, dvy = k6 - q6;
        const float dist = sqtf(dpx * dpx + dpy * dpy + 1e-6f);
        float f8[8];
        // c8=0: dist^(1,2,4,8); keep 4 values for the c8=6 reuse
        four4(dist, f8);
        const float ds1 = f8[0], ds2 = f8[1], dc1 = f8[4], dc2 = f8[5];
        fstore(0, f8);
        // c8=1: inv_dist
        four4(rcpf(dist + 0.1f), f8);
        fstore(1, f8);
        // c8=2,3: ata | aspect
        {
            const float inv_d2 = rcpf(dist + 1e-6f);
            const float bx = dpx * inv_d2, by = dpy * inv_d2;
            four4(bx * q7 + by * q8, f8); fstore(2, f8);
            four4(bx * k7 + by * k8, f8); fstore(3, f8);
        }
        // c8=4: dpx|dpy ; c8=5: dvx|dvy
        four2(dpx, f8); four2(dpy, f8 + 4); fstore(4, f8);
        four2(dvx, f8); four2(dvy, f8 + 4); fstore(5, f8);
        // c8=6: ttca | dist-reuse
        {
            const float dd = dpx * dvx + dpy * dvy;
            const float ss = dvx * dvx + dvy * dvy;
            // tanh(relu(z)) = 1 - 2/(1 + 2^(2*log2e*z)), z >= 0
            const float z = fmaxf(0.f, -dd * rcpf(ss + 1e-6f));
            const float ttca = 1.f - 2.f * rcpf(1.f + ex2f(2.88539008f * z));
            four2(ttca, f8);
            f8[4] = ds1; f8[5] = ds2; f8[6] = dc1; f8[7] = dc2;
            fstore(6, f8);
        }
        // c8=7: same_team consts | delta_speed
        {
            const bool st = (q0 == k0);
            f8[0] = st ? 0.84147098f : 0.f;      // sin(1)/sin(0)
            f8[1] = st ? 0.90929743f : 0.f;      // sin(2)/sin(0)
            f8[2] = st ? 0.54030231f : 1.f;      // cos(1)/cos(0)
            f8[3] = st ? -0.41614684f : 1.f;     // cos(2)/cos(0)
            const float qs = sqtf(q5 * q5 + q6 * q6);
            four2(k_speed - qs, f8 + 4);
            fstore(7, f8);
        }
    };

    // ---- prologue: features(row 0) by waves 4-7 ----
    if (wave >= 4)
        feat_full(i0);
    __syncthreads();   // feat_s(row 0) ready

    // ================= row loop: 4 query rows =================
#pragma unroll 1
    for (int row = 0; row < ROWS_PER_BLK; ++row) {
        const int i = i0 + row;

        // ---- 4 chunks of 64 pairs ----
#pragma unroll 1
        for (int c = 0; c < 4; ++c) {
            const int p0 = c * 64;

            // GEMM1': bias rides as C-in on the ks=0 MFMAs
            f32x4 acc[2][4];
#pragma unroll
            for (int mt = 0; mt < 4; ++mt) {
                const int r2 = p0 + mt * 16 + lane15;
                const bf16x8 fb = *(const bf16x8*)
                    &feat_s[r2 * FSTRIDE + ((quad ^ swr) * 8)];
                acc[0][mt] = __builtin_amdgcn_mfma_f32_16x16x32_bf16(
                    w1f[0][0], fb, b1c[0], 0, 0, 0);
                acc[1][mt] = __builtin_amdgcn_mfma_f32_16x16x32_bf16(
                    w1f[1][0], fb, b1c[1], 0, 0, 0);
            }
#pragma unroll
            for (int mt = 0; mt < 4; ++mt) {
                const int r2 = p0 + mt * 16 + lane15;
                const bf16x8 fb = *(const bf16x8*)
                    &feat_s[r2 * FSTRIDE + (((4 + quad) ^ swr) * 8)];
#pragma unroll
                for (int nt = 0; nt < 2; ++nt)
                    acc[nt][mt] = __builtin_amdgcn_mfma_f32_16x16x32_bf16(
                        w1f[nt][1], fb, acc[nt][mt], 0, 0, 0);
            }

            // silu-COMPUTE into regs (no LDS): packed-f32 add/mul
            uint2 pk[2][4];
#pragma unroll
            for (int nt = 0; nt < 2; ++nt)
#pragma unroll
                for (int mt = 0; mt < 4; ++mt) {
                    const f32x4 a = acc[nt][mt];     // = -log2e * preact
                    const f32x2 a01 = {a[0], a[1]}, a23 = {a[2], a[3]};
                    const f32x2 e01 = {ex2f(a[0]), ex2f(a[1])};
                    const f32x2 e23 = {ex2f(a[2]), ex2f(a[3])};
                    const f32x2 t01 = e01 + one2;    // v_pk_add_f32
                    const f32x2 t23 = e23 + one2;
                    const f32x2 r01 = {rcpf(t01[0]), rcpf(t01[1])};
                    const f32x2 r23 = {rcpf(t23[0]), rcpf(t23[1])};
                    const f32x2 s01 = a01 * r01;     // v_pk_mul_f32
                    const f32x2 s23 = a23 * r23;     // = -1.4427*silu
                    pk[nt][mt].x = cvtpk(s01[0], s01[1]);
                    pk[nt][mt].y = cvtpk(s23[0], s23[1]);
                }

            __syncthreads();  // barrier#1: h_s(prev) fully consumed

            // only the 8 ds_write_b64 live between the barriers
#pragma unroll
            for (int nt = 0; nt < 2; ++nt)
#pragma unroll
                for (int mt = 0; mt < 4; ++mt) {
                    const int pair = mt * 16 + lane15;
                    const int hbase = n0 + nt * 16 + quad * 4;
                    *(uint2*)&h_s[pair * HSTRIDE + hbase] = pk[nt][mt];
                }
            __syncthreads();  // barrier#2: h_s(c) ready

            // post-bar2: waves 0-3 -> GEMM2(c); waves 4-7 at c==3 ->
            // features(row+1) over the now-dead feat_s(row).
            if (wave < 4) {
                const int pw = wave * 16;
                f32x4 acc2 = (f32x4){b2v, b2v, b2v, b2v};
#pragma unroll
                for (int ks = 0; ks < 8; ++ks) {
                    const bf16x8 ha = *(const bf16x8*)&h_s[(pw + lane15) * HSTRIDE
                                                            + ks * 32 + quad * 8];
                    acc2 = __builtin_amdgcn_mfma_f32_16x16x32_bf16(ha, w2f[ks], acc2, 0, 0, 0);
                }
                if (lane15 < NH) {
                    float* op = outp + (size_t)i * NK + p0;
                    *(float4*)op = make_float4(acc2[0], acc2[1], acc2[2], acc2[3]);
                }
            } else if (c == 3 && row + 1 < ROWS_PER_BLK) {
                feat_full(i + 1);
            }
            // no end barrier: next chunk's GEMM1' touches only feat_s(row)
        }

        // rollover: seals feat_s(row+1) writes before G1(row+1, c0)
        if (row + 1 < ROWS_PER_BLK)
            __syncthreads();
    }
}

extern "C" void kernel_launch(void* const* d_in, const int* in_sizes, int n_in,
                              void* d_out, int out_size, void* d_ws, size_t ws_size,
                              hipStream_t stream) {
    const float* q  = (const float*)d_in[0];
    const float* k  = (const float*)d_in[1];
    const float* W1 = (const float*)d_in[2];
    const float* b1 = (const float*)d_in[3];
    const float* W2 = (const float*)d_in[4];
    const float* b2 = (const float*)d_in[5];
    float* out = (float*)d_out;

    dim3 grid(NB * NQ / ROWS_PER_BLK);  // 512 blocks = 2/CU, one dispatch round
    dim3 block(512);                    // 8 waves: 16 waves/CU resident
    relfeat_mfma_kernel<<<grid, block, 0, stream>>>(q, k, W1, b1, W2, b2, out);
}